// Round 1
// baseline (183.257 us; speedup 1.0000x reference)
//
#include <hip/hip_runtime.h>
#include <hip/hip_bf16.h>
#include <math.h>

// Problem constants (ModernBERT attention)
#define BATCH 4
#define SEQ   2048
#define DMODEL 768
#define NHEADS 12
#define HDIM  64
#define WIN   64          // window each side
#define QKV_LD 2304       // 3*DMODEL

typedef __attribute__((ext_vector_type(8))) short bf16x8;  // 8 bf16 = 4 VGPRs
typedef __attribute__((ext_vector_type(4))) float f32x4;

typedef __attribute__((address_space(1))) const unsigned int guint;
typedef __attribute__((address_space(3))) unsigned int luint;

__device__ inline void gl_lds16(const __hip_bfloat16* g, __hip_bfloat16* l) {
    __builtin_amdgcn_global_load_lds((guint*)g, (luint*)l, 16, 0, 0);
}

__device__ inline void to_out(float* p, float v) { *p = v; }
__device__ inline void to_out(__hip_bfloat16* p, float v) { *p = __float2bfloat16(v); }

// ---------------------------------------------------------------------------
// fused setup: cast hidden/Wqkv/Wo to bf16 + build rope cos/sin table.
// ---------------------------------------------------------------------------
#define N4_HID  (BATCH * SEQ * DMODEL / 4)     // 1,572,864
#define N4_WQKV (QKV_LD * DMODEL / 4)          //   442,368
#define N4_WO   (DMODEL * DMODEL / 4)          //   147,456
#define N_ROPE  (SEQ * 32)                     //    65,536
#define SETUP_TOTAL (N4_HID + N4_WQKV + N4_WO + N_ROPE)

__device__ inline void cast4(const float* in, __hip_bfloat16* out, int i) {
    float4 v = ((const float4*)in)[i];
    union { ushort4 u; __hip_bfloat16 h[4]; } o;
    o.h[0] = __float2bfloat16(v.x); o.h[1] = __float2bfloat16(v.y);
    o.h[2] = __float2bfloat16(v.z); o.h[3] = __float2bfloat16(v.w);
    ((ushort4*)out)[i] = o.u;
}

__global__ __launch_bounds__(256) void setup_kernel(const float* __restrict__ hidden,
                                                    const float* __restrict__ Wqkv,
                                                    const float* __restrict__ Wo,
                                                    __hip_bfloat16* __restrict__ hid_bf,
                                                    __hip_bfloat16* __restrict__ wqkv_bf,
                                                    __hip_bfloat16* __restrict__ wo_bf,
                                                    float2* __restrict__ tab) {
    int id = blockIdx.x * 256 + threadIdx.x;
    if (id < N4_HID) {
        cast4(hidden, hid_bf, id);
    } else if (id < N4_HID + N4_WQKV) {
        cast4(Wqkv, wqkv_bf, id - N4_HID);
    } else if (id < N4_HID + N4_WQKV + N4_WO) {
        cast4(Wo, wo_bf, id - N4_HID - N4_WQKV);
    } else if (id < SETUP_TOTAL) {
        int idx = id - (N4_HID + N4_WQKV + N4_WO);
        int t = idx >> 5, j = idx & 31;
        const float L2T_OVER_32 = 13.287712379549449f / 32.0f;  // log2(10000)/32
        float inv = exp2f(-(float)j * L2T_OVER_32);
        float s, c;
        sincosf((float)t * inv, &s, &c);
        tab[idx] = make_float2(c, s);
    }
}

// ---------------------------------------------------------------------------
// bf16 MFMA NT GEMM: C[m,n] = sum_k A[m*lda+k]*B[n*ldb+k]
// BM=128, BN=64*NWN (NWN=2 -> 128x128, 2x2 waves; NWN=1 -> 128x64, 4x1 waves).
// BK=64, global_load_lds staging with XOR-swizzled source chunks -> fragment
// ds_read_b128 conflict-free (verified R5: conflicts 3.5M -> 147K).
// Epilogue: direct per-lane scalar stores, NO barriers (R5's LDS-patch
// epilogue regressed 57->68 us from its 8 block barriers).
// XCD-aware 1D grid: XCD (bid&7) owns m-tiles [8x,8x+8) for all n-tiles.
// Optional fused RoPE epilogue on q/k columns (rope_tab != nullptr).
// ---------------------------------------------------------------------------
template <typename OutT, int NWN>
__global__ __launch_bounds__(256) void gemm_nt_bf16(const __hip_bfloat16* __restrict__ A,
                                                    const __hip_bfloat16* __restrict__ B,
                                                    OutT* __restrict__ C,
                                                    int lda, int ldb, int ldc, int K,
                                                    const float2* __restrict__ rope_tab) {
    constexpr int BN  = 64 * NWN;     // 128 or 64
    constexpr int NWM = 4 / NWN;      // 2 or 4
    constexpr int WM  = 128 / NWM;    // 64 or 32
    constexpr int MI  = WM / 16;      // 4 or 2

    __shared__ __align__(16) __hip_bfloat16 As[128 * 64];   // 16 KB
    __shared__ __align__(16) __hip_bfloat16 Bs[BN * 64];    // 16 or 8 KB

    const int tid  = threadIdx.x;
    const int lane = tid & 63;
    const int wave = tid >> 6;
    const int wm   = wave / NWN;
    const int wn   = wave % NWN;
    const int fr   = lane & 15;
    const int quad = lane >> 4;

    // XCD-aware swizzle (gridM = 64 m-tiles, 8 per XCD)
    const int bid = blockIdx.x;
    const int x   = bid & 7;
    const int j   = bid >> 3;
    const int m0  = (x * 8 + (j & 7)) * 128;
    const int n0  = (j >> 3) * BN;

    f32x4 acc[MI][4];
#pragma unroll
    for (int i = 0; i < MI; i++)
#pragma unroll
        for (int jj = 0; jj < 4; jj++) acc[i][jj] = (f32x4){0.f, 0.f, 0.f, 0.f};

    for (int k0 = 0; k0 < K; k0 += 64) {
        __syncthreads();
        // A tile 128x64 = 1024 16B-chunks, 4 insts/wave; B tile BN x 64.
        // LDS addr = t*16 (lane-linear, required by global_load_lds);
        // global source chunk XOR-permuted within the row.
#pragma unroll
        for (int c = 0; c < 4; c++) {
            int t = (wave * 4 + c) * 64 + lane;      // 0..1023
            int row = t >> 3, ch = t & 7;
            int gcol = (ch ^ (row & 7)) * 8;
            gl_lds16(A + (size_t)(m0 + row) * lda + k0 + gcol, As + t * 8);
        }
#pragma unroll
        for (int c = 0; c < 2 * NWN; c++) {
            int t = (wave * 2 * NWN + c) * 64 + lane;
            int row = t >> 3, ch = t & 7;
            int gcol = (ch ^ (row & 7)) * 8;
            gl_lds16(B + (size_t)(n0 + row) * ldb + k0 + gcol, Bs + t * 8);
        }
        __syncthreads();

#pragma unroll
        for (int ks = 0; ks < 2; ks++) {
            bf16x8 af[MI], bf_[4];
#pragma unroll
            for (int mi = 0; mi < MI; mi++) {
                int row = wm * WM + mi * 16 + fr;
                int pos = (ks * 4 + quad) ^ (row & 7);
                af[mi] = *(const bf16x8*)(As + row * 64 + pos * 8);
            }
#pragma unroll
            for (int ni = 0; ni < 4; ni++) {
                int row = wn * 64 + ni * 16 + fr;
                int pos = (ks * 4 + quad) ^ (row & 7);
                bf_[ni] = *(const bf16x8*)(Bs + row * 64 + pos * 8);
            }
#pragma unroll
            for (int mi = 0; mi < MI; mi++)
#pragma unroll
                for (int ni = 0; ni < 4; ni++)
                    acc[mi][ni] = __builtin_amdgcn_mfma_f32_16x16x32_bf16(af[mi], bf_[ni], acc[mi][ni], 0, 0, 0);
        }
    }

    // fused RoPE: 64-col group b0 covers exactly one head; pairs (ni, ni+2)
    const int b0 = n0 + wn * 64;
    if (rope_tab != nullptr && b0 < 2 * DMODEL) {
#pragma unroll
        for (int mi = 0; mi < MI; mi++) {
#pragma unroll
            for (int r = 0; r < 4; r++) {
                int t = (m0 + wm * WM + mi * 16 + quad * 4 + r) & (SEQ - 1);
#pragma unroll
                for (int ni = 0; ni < 2; ni++) {
                    float2 cs = rope_tab[t * 32 + ni * 16 + fr];
                    float x0 = acc[mi][ni][r], x1 = acc[mi][ni + 2][r];
                    acc[mi][ni][r]     = x0 * cs.x - x1 * cs.y;
                    acc[mi][ni + 2][r] = x0 * cs.y + x1 * cs.x;
                }
            }
        }
    }

    // direct scalar-store epilogue (no barriers)
#pragma unroll
    for (int mi = 0; mi < MI; mi++)
#pragma unroll
        for (int ni = 0; ni < 4; ni++) {
            f32x4 v = acc[mi][ni];
            int gc = b0 + ni * 16 + fr;
            size_t rbase = (size_t)(m0 + wm * WM + mi * 16 + quad * 4);
#pragma unroll
            for (int r = 0; r < 4; r++)
                to_out(&C[(rbase + r) * ldc + gc], v[r]);
        }
}

// ---------------------------------------------------------------------------
// Sliding-window attention, one block per (b, head, 64-query tile).
// QK^T and PV via MFMA; in-register softmax via quad-group shuffles.
// Q fragments loaded directly from global. K staged stride 64 + XOR swizzle.
// LDS 48 KB -> 3 blocks/CU.
// ---------------------------------------------------------------------------
#define PLD  192

__global__ __launch_bounds__(256) void attn_kernel(const __hip_bfloat16* __restrict__ qkv,
                                                   const int* __restrict__ mask,
                                                   __hip_bfloat16* __restrict__ attn) {
    __shared__ __align__(16) char smem[49152];
    __hip_bfloat16* Ks = (__hip_bfloat16*)smem;            // [192][64] swizzled
    __hip_bfloat16* Pb = (__hip_bfloat16*)smem;            // [64][192] swizzled (aliases Ks)
    __hip_bfloat16* Vt = (__hip_bfloat16*)(smem + 24576);  // [64][192] swizzled

    const int tid  = threadIdx.x;
    const int lane = tid & 63;
    const int wave = tid >> 6;
    const int fr   = lane & 15;
    const int quad = lane >> 4;

    // XCD-aware swizzle: 1536 blocks = 8 XCDs x 192
    const int bid  = blockIdx.x;
    const int x    = bid & 7;
    const int j    = bid >> 3;                 // 0..191
    const int b    = x >> 1;
    const int q0   = ((x & 1) * 16 + (j & 15)) * 64;
    const int head = j >> 4;                   // 0..11

    const int klo = max(0, q0 - WIN);
    const int khi = min(SEQ, q0 + 64 + WIN);
    const int nk  = khi - klo;     // 128 or 192
    const int nt  = nk >> 4;       // 8 or 12
    const int nkc = nk >> 5;       // 4 or 6

    const size_t rowbase = (size_t)(b * SEQ) * QKV_LD + head * HDIM;

    // ---- stage K [nk][64] XOR-swizzled: up to 1536 uint4 tasks
    for (int task = tid; task < nk * 8; task += 256) {
        int row = task >> 3, g = task & 7;
        uint4 v = *(const uint4*)(qkv + rowbase + (size_t)(klo + row) * QKV_LD + DMODEL + g * 8);
        *(uint4*)(Ks + row * 64 + (g ^ (row & 7)) * 8) = v;
    }
    // ---- stage V transposed [64][nk], XOR-swizzled chunks of 8
    {
        int h = lane;
        const __hip_bfloat16* vb = qkv + rowbase + 2 * DMODEL + h;
        int ng = nk >> 3;
        for (int g = wave; g < ng; g += 4) {
            unsigned int u0, u1, u2, u3;
            {
                unsigned short a0 = *(const unsigned short*)(vb + (size_t)(klo + g * 8 + 0) * QKV_LD);
                unsigned short a1 = *(const unsigned short*)(vb + (size_t)(klo + g * 8 + 1) * QKV_LD);
                unsigned short a2 = *(const unsigned short*)(vb + (size_t)(klo + g * 8 + 2) * QKV_LD);
                unsigned short a3 = *(const unsigned short*)(vb + (size_t)(klo + g * 8 + 3) * QKV_LD);
                unsigned short a4 = *(const unsigned short*)(vb + (size_t)(klo + g * 8 + 4) * QKV_LD);
                unsigned short a5 = *(const unsigned short*)(vb + (size_t)(klo + g * 8 + 5) * QKV_LD);
                unsigned short a6 = *(const unsigned short*)(vb + (size_t)(klo + g * 8 + 6) * QKV_LD);
                unsigned short a7 = *(const unsigned short*)(vb + (size_t)(klo + g * 8 + 7) * QKV_LD);
                u0 = (unsigned int)a0 | ((unsigned int)a1 << 16);
                u1 = (unsigned int)a2 | ((unsigned int)a3 << 16);
                u2 = (unsigned int)a4 | ((unsigned int)a5 << 16);
                u3 = (unsigned int)a6 | ((unsigned int)a7 << 16);
            }
            int cs = g ^ (h & 7);
            *(uint4*)(Vt + h * PLD + cs * 8) = make_uint4(u0, u1, u2, u3);
        }
    }

    // ---- Q fragments direct from global (A-layout: row=fr, k=quad*8+j)
    const int qrow0 = q0 + wave * 16;
    bf16x8 aq0 = *(const bf16x8*)(qkv + rowbase + (size_t)(qrow0 + fr) * QKV_LD + quad * 8);
    bf16x8 aq1 = *(const bf16x8*)(qkv + rowbase + (size_t)(qrow0 + fr) * QKV_LD + 32 + quad * 8);

    const int* mb = mask + b * SEQ;
    int mq[4];
#pragma unroll
    for (int r = 0; r < 4; r++) mq[r] = mb[qrow0 + quad * 4 + r];

    __syncthreads();

    // ---- QK^T via MFMA over key tiles
    f32x4 sc[12];
#pragma unroll
    for (int kt = 0; kt < 12; kt++) sc[kt] = (f32x4){-1e30f, -1e30f, -1e30f, -1e30f};

#pragma unroll
    for (int kt = 0; kt < 12; kt++) {
        if (kt < nt) {
            int krow = kt * 16 + fr;
            int kg = klo + krow;
            int p0 = (quad) ^ (krow & 7);
            int p1 = (4 + quad) ^ (krow & 7);
            bf16x8 bk0 = *(const bf16x8*)(Ks + krow * 64 + p0 * 8);
            bf16x8 bk1 = *(const bf16x8*)(Ks + krow * 64 + p1 * 8);
            f32x4 a = (f32x4){0.f, 0.f, 0.f, 0.f};
            a = __builtin_amdgcn_mfma_f32_16x16x32_bf16(aq0, bk0, a, 0, 0, 0);
            a = __builtin_amdgcn_mfma_f32_16x16x32_bf16(aq1, bk1, a, 0, 0, 0);
            int mk = mb[kg];
            f32x4 s;
#pragma unroll
            for (int r = 0; r < 4; r++) {
                int qg = qrow0 + quad * 4 + r;
                bool ok = (abs(qg - kg) <= WIN) && (mk != 0) && (mq[r] != 0);
                s[r] = ok ? a[r] * 0.125f : -1e30f;
            }
            sc[kt] = s;
        }
    }

    // ---- in-register softmax: reduce across fr lanes (same quad group)
    f32x4 mx = sc[0];
#pragma unroll
    for (int kt = 1; kt < 12; kt++)
#pragma unroll
        for (int r = 0; r < 4; r++) mx[r] = fmaxf(mx[r], sc[kt][r]);
#pragma unroll
    for (int off = 8; off >= 1; off >>= 1)
#pragma unroll
        for (int r = 0; r < 4; r++) mx[r] = fmaxf(mx[r], __shfl_xor(mx[r], off));

    f32x4 sum = (f32x4){0.f, 0.f, 0.f, 0.f};
#pragma unroll
    for (int kt = 0; kt < 12; kt++)
#pragma unroll
        for (int r = 0; r < 4; r++) {
            float e = __expf(sc[kt][r] - mx[r]);
            sc[kt][r] = e;
            sum[r] += e;
        }
#pragma unroll
    for (int off = 8; off >= 1; off >>= 1)
#pragma unroll
        for (int r = 0; r < 4; r++) sum[r] += __shfl_xor(sum[r], off);
    f32x4 rs;
#pragma unroll
    for (int r = 0; r < 4; r++) rs[r] = 1.0f / sum[r];

    // ---- write P (bf16, A-layout-friendly, swizzled) into Ks space
    __syncthreads();   // all waves done reading Ks
#pragma unroll
    for (int kt = 0; kt < 12; kt++) {
        if (kt < nt) {
#pragma unroll
            for (int r = 0; r < 4; r++) {
                int prow = wave * 16 + quad * 4 + r;
                int c = kt * 2 + (fr >> 3);
                int cs = c ^ (prow & 7);
                Pb[prow * PLD + cs * 8 + (fr & 7)] = __float2bfloat16(sc[kt][r] * rs[r]);
            }
        }
    }
    __syncthreads();

    // ---- PV via MFMA: O[16q][64h] per wave
    f32x4 o[4];
#pragma unroll
    for (int ht = 0; ht < 4; ht++) o[ht] = (f32x4){0.f, 0.f, 0.f, 0.f};

#pragma unroll
    for (int kc = 0; kc < 6; kc++) {
        if (kc < nkc) {
            int cs = (kc * 4 + quad) ^ (fr & 7);
            bf16x8 ap = *(const bf16x8*)(Pb + (wave * 16 + fr) * PLD + cs * 8);
#pragma unroll
            for (int ht = 0; ht < 4; ht++) {
                bf16x8 bv = *(const bf16x8*)(Vt + (ht * 16 + fr) * PLD + cs * 8);
                o[ht] = __builtin_amdgcn_mfma_f32_16x16x32_bf16(ap, bv, o[ht], 0, 0, 0);
            }
        }
    }

    // ---- store O (bf16) to attn [B*T, 768]
    __hip_bfloat16* ob = attn + (size_t)(b * SEQ + qrow0) * DMODEL + head * HDIM;
#pragma unroll
    for (int r = 0; r < 4; r++)
#pragma unroll
        for (int ht = 0; ht < 4; ht++)
            ob[(size_t)(quad * 4 + r) * DMODEL + ht * 16 + fr] = __float2bfloat16(o[ht][r]);
}

// ---------------------------------------------------------------------------
extern "C" void kernel_launch(void* const* d_in, const int* in_sizes, int n_in,
                              void* d_out, int out_size, void* d_ws, size_t ws_size,
                              hipStream_t stream) {
    const float* hidden = (const float*)d_in[0];
    const int*   mask   = (const int*)d_in[1];
    const float* Wqkv   = (const float*)d_in[2];
    const float* Wo     = (const float*)d_in[3];
    float* out = (float*)d_out;

    char* w = (char*)d_ws;
    __hip_bfloat16* qkv_bf  = (__hip_bfloat16*)(w);              // 37,748,736
    __hip_bfloat16* hid_bf  = (__hip_bfloat16*)(w + 37748736);   // 12,582,912
    __hip_bfloat16* wqkv_bf = (__hip_bfloat16*)(w + 50331648);   //  3,538,944
    __hip_bfloat16* wo_bf   = (__hip_bfloat16*)(w + 53870592);   //  1,179,648
    __hip_bfloat16* attn_bf = (__hip_bfloat16*)(w + 55050240);   // 12,582,912
    float2*         tab     = (float2*)(w + 67633152);           //    524,288

    // 0) fused setup: casts + rope table (one launch)
    setup_kernel<<<SETUP_TOTAL / 256, 256, 0, stream>>>(hidden, Wqkv, Wo,
                                                        hid_bf, wqkv_bf, wo_bf, tab);

    // 1) QKV projection + fused RoPE (128x128 tiles, 18 n-tiles x 64 m-tiles)
    gemm_nt_bf16<__hip_bfloat16, 2><<<18 * 64, 256, 0, stream>>>(hid_bf, wqkv_bf, qkv_bf,
                                                                 DMODEL, DMODEL, QKV_LD, DMODEL, tab);

    // 2) sliding-window attention (XCD-swizzled 1D grid)
    attn_kernel<<<(SEQ / 64) * NHEADS * BATCH, 256, 0, stream>>>(qkv_bf, mask, attn_bf);

    // 3) output projection (128x64 tiles -> 768 blocks = 3 blocks/CU)
    gemm_nt_bf16<float, 1><<<12 * 64, 256, 0, stream>>>(attn_bf, wo_bf, out,
                                                        DMODEL, DMODEL, DMODEL, DMODEL, nullptr);
}

// Round 2
// 170.327 us; speedup vs baseline: 1.0759x; 1.0759x over previous
//
#include <hip/hip_runtime.h>
#include <hip/hip_bf16.h>
#include <math.h>

// Problem constants (ModernBERT attention)
#define BATCH 4
#define SEQ   2048
#define DMODEL 768
#define NHEADS 12
#define HDIM  64
#define WIN   64          // window each side
#define QKV_LD 2304       // 3*DMODEL

typedef __attribute__((ext_vector_type(8))) short bf16x8;  // 8 bf16 = 4 VGPRs
typedef __attribute__((ext_vector_type(4))) float f32x4;

typedef __attribute__((address_space(1))) const unsigned int guint;
typedef __attribute__((address_space(3))) unsigned int luint;

__device__ inline void gl_lds16(const __hip_bfloat16* g, __hip_bfloat16* l) {
    __builtin_amdgcn_global_load_lds((guint*)g, (luint*)l, 16, 0, 0);
}

__device__ inline void to_out(float* p, float v) { *p = v; }
__device__ inline void to_out(__hip_bfloat16* p, float v) { *p = __float2bfloat16(v); }

// ---------------------------------------------------------------------------
// fused setup: cast hidden/Wqkv/Wo to bf16 + build rope cos/sin table.
// ---------------------------------------------------------------------------
#define N4_HID  (BATCH * SEQ * DMODEL / 4)     // 1,572,864
#define N4_WQKV (QKV_LD * DMODEL / 4)          //   442,368
#define N4_WO   (DMODEL * DMODEL / 4)          //   147,456
#define N_ROPE  (SEQ * 32)                     //    65,536
#define SETUP_TOTAL (N4_HID + N4_WQKV + N4_WO + N_ROPE)

__device__ inline void cast4(const float* in, __hip_bfloat16* out, int i) {
    float4 v = ((const float4*)in)[i];
    union { ushort4 u; __hip_bfloat16 h[4]; } o;
    o.h[0] = __float2bfloat16(v.x); o.h[1] = __float2bfloat16(v.y);
    o.h[2] = __float2bfloat16(v.z); o.h[3] = __float2bfloat16(v.w);
    ((ushort4*)out)[i] = o.u;
}

__global__ __launch_bounds__(256) void setup_kernel(const float* __restrict__ hidden,
                                                    const float* __restrict__ Wqkv,
                                                    const float* __restrict__ Wo,
                                                    __hip_bfloat16* __restrict__ hid_bf,
                                                    __hip_bfloat16* __restrict__ wqkv_bf,
                                                    __hip_bfloat16* __restrict__ wo_bf,
                                                    float2* __restrict__ tab) {
    int id = blockIdx.x * 256 + threadIdx.x;
    if (id < N4_HID) {
        cast4(hidden, hid_bf, id);
    } else if (id < N4_HID + N4_WQKV) {
        cast4(Wqkv, wqkv_bf, id - N4_HID);
    } else if (id < N4_HID + N4_WQKV + N4_WO) {
        cast4(Wo, wo_bf, id - N4_HID - N4_WQKV);
    } else if (id < SETUP_TOTAL) {
        int idx = id - (N4_HID + N4_WQKV + N4_WO);
        int t = idx >> 5, j = idx & 31;
        const float L2T_OVER_32 = 13.287712379549449f / 32.0f;  // log2(10000)/32
        float inv = exp2f(-(float)j * L2T_OVER_32);
        float s, c;
        sincosf((float)t * inv, &s, &c);
        tab[idx] = make_float2(c, s);
    }
}

// ---------------------------------------------------------------------------
// Pipelined bf16 MFMA NT GEMM: C[m,n] = sum_k A[m*lda+k]*B[n*ldb+k]
// BM=128, BN=128, BK=64, K=768 fixed (12 K-tiles). 512 threads = 8 waves,
// wave decomposition 4M x 2N -> per-wave 32x64 output (keeps 64-col head
// groups within one wave for the fused RoPE epilogue).
// 4-slot LDS ring (4 x 16KB A + 4 x 16KB B = 128 KB): stage tile t+3 while
// computing tile t; per-wave counted s_waitcnt vmcnt(8) (2 tiles in flight)
// + RAW s_barrier (no implicit vmcnt(0) drain, unlike __syncthreads).
// Tail: vmcnt(4) at t=10, vmcnt(0) at t=11. Slot (t+3)&3 == (t-1)&3 is
// provably dead after the iter-t barrier (all waves consumed tile t-1 into
// registers before reaching it; compiler lgkmcnt precedes the MFMAs).
// Staging/fragment XOR-8 swizzle identical to the verified R5 kernel:
// LDS(row,ch) holds global chunk ch^(row&7); read pos = (ks*4+quad)^(row&7).
// setprio(1) around the 16-MFMA cluster (T5: pays on phase-split schedules).
// XCD-aware 1D grid: gridM = 64 m-tiles, XCD (bid&7) owns m-tiles [8x,8x+8).
// ---------------------------------------------------------------------------
template <typename OutT, bool ROPE>
__global__ __launch_bounds__(512) void gemm_pipe(const __hip_bfloat16* __restrict__ A,
                                                 const __hip_bfloat16* __restrict__ B,
                                                 OutT* __restrict__ C,
                                                 int lda, int ldb, int ldc,
                                                 const float2* __restrict__ rope_tab) {
    __shared__ __align__(16) char smem[131072];
    __hip_bfloat16* As = (__hip_bfloat16*)smem;            // [4][128*64]
    __hip_bfloat16* Bs = (__hip_bfloat16*)(smem + 65536);  // [4][128*64]

    const int tid  = threadIdx.x;
    const int lane = tid & 63;
    const int wave = tid >> 6;   // 0..7
    const int wm   = wave >> 1;  // 0..3  (32-row band)
    const int wn   = wave & 1;   // 0..1  (64-col band)
    const int fr   = lane & 15;
    const int quad = lane >> 4;

    // XCD-aware swizzle (gridM = 64 m-tiles, 8 per XCD)
    const int bid = blockIdx.x;
    const int x   = bid & 7;
    const int j   = bid >> 3;
    const int m0  = (x * 8 + (j & 7)) * 128;
    const int n0  = (j >> 3) * 128;

    f32x4 acc[2][4];
#pragma unroll
    for (int i = 0; i < 2; i++)
#pragma unroll
        for (int jj = 0; jj < 4; jj++) acc[i][jj] = (f32x4){0.f, 0.f, 0.f, 0.f};

    // stage one 128x64 A-tile + 128x64 B-tile into ring slot t&3.
    // 1024 16B-chunks each over 512 threads -> 2 A + 2 B loads per thread.
    auto stage = [&](int t) {
        const int s  = t & 3;
        const int k0 = t * 64;
#pragma unroll
        for (int c = 0; c < 2; ++c) {
            int tc  = c * 512 + tid;          // 0..1023
            int row = tc >> 3, ch = tc & 7;
            int gcol = (ch ^ (row & 7)) * 8;
            gl_lds16(A + (size_t)(m0 + row) * lda + k0 + gcol, As + s * 8192 + tc * 8);
            gl_lds16(B + (size_t)(n0 + row) * ldb + k0 + gcol, Bs + s * 8192 + tc * 8);
        }
    };

    // prologue: 3 tiles in flight (12 loads/wave)
    stage(0); stage(1); stage(2);

#pragma unroll
    for (int t = 0; t < 12; ++t) {
        // retire tile t's 4 loads (wave-local); keep up to 2 tiles in flight.
        if (t < 10)       asm volatile("s_waitcnt vmcnt(8)" ::: "memory");
        else if (t == 10) asm volatile("s_waitcnt vmcnt(4)" ::: "memory");
        else              asm volatile("s_waitcnt vmcnt(0)" ::: "memory");
        __builtin_amdgcn_s_barrier();          // raw: no implicit drain
        __builtin_amdgcn_sched_barrier(0);     // pin: no reads hoisted above

        if (t < 9) stage(t + 3);               // overwrites slot of tile t-1 (dead)

        const __hip_bfloat16* as = As + (t & 3) * 8192;
        const __hip_bfloat16* bs = Bs + (t & 3) * 8192;
        bf16x8 af[2][2], bfv[2][4];
#pragma unroll
        for (int ks = 0; ks < 2; ++ks) {
#pragma unroll
            for (int mi = 0; mi < 2; ++mi) {
                int row = wm * 32 + mi * 16 + fr;
                int pos = (ks * 4 + quad) ^ (row & 7);
                af[ks][mi] = *(const bf16x8*)(as + row * 64 + pos * 8);
            }
#pragma unroll
            for (int ni = 0; ni < 4; ++ni) {
                int row = wn * 64 + ni * 16 + fr;
                int pos = (ks * 4 + quad) ^ (row & 7);
                bfv[ks][ni] = *(const bf16x8*)(bs + row * 64 + pos * 8);
            }
        }

        __builtin_amdgcn_s_setprio(1);
#pragma unroll
        for (int ks = 0; ks < 2; ++ks)
#pragma unroll
            for (int mi = 0; mi < 2; ++mi)
#pragma unroll
                for (int ni = 0; ni < 4; ++ni)
                    acc[mi][ni] = __builtin_amdgcn_mfma_f32_16x16x32_bf16(af[ks][mi], bfv[ks][ni], acc[mi][ni], 0, 0, 0);
        __builtin_amdgcn_s_setprio(0);
    }

    // fused RoPE: 64-col group b0 covers exactly one head; pairs (ni, ni+2)
    const int b0 = n0 + wn * 64;
    if (ROPE && b0 < 2 * DMODEL) {
#pragma unroll
        for (int mi = 0; mi < 2; mi++) {
#pragma unroll
            for (int r = 0; r < 4; r++) {
                int t = (m0 + wm * 32 + mi * 16 + quad * 4 + r) & (SEQ - 1);
#pragma unroll
                for (int ni = 0; ni < 2; ni++) {
                    float2 cs = rope_tab[t * 32 + ni * 16 + fr];
                    float x0 = acc[mi][ni][r], x1 = acc[mi][ni + 2][r];
                    acc[mi][ni][r]     = x0 * cs.x - x1 * cs.y;
                    acc[mi][ni + 2][r] = x0 * cs.y + x1 * cs.x;
                }
            }
        }
    }

    // direct scalar-store epilogue (no barriers)
#pragma unroll
    for (int mi = 0; mi < 2; mi++)
#pragma unroll
        for (int ni = 0; ni < 4; ni++) {
            f32x4 v = acc[mi][ni];
            int gc = b0 + ni * 16 + fr;
            size_t rbase = (size_t)(m0 + wm * 32 + mi * 16 + quad * 4);
#pragma unroll
            for (int r = 0; r < 4; r++)
                to_out(&C[(rbase + r) * ldc + gc], v[r]);
        }
}

// ---------------------------------------------------------------------------
// Sliding-window attention, one block per (b, head, 64-query tile).
// QK^T and PV via MFMA; in-register softmax via quad-group shuffles.
// Q fragments loaded directly from global. K staged stride 64 + XOR swizzle.
// LDS 48 KB -> 3 blocks/CU.
// ---------------------------------------------------------------------------
#define PLD  192

__global__ __launch_bounds__(256) void attn_kernel(const __hip_bfloat16* __restrict__ qkv,
                                                   const int* __restrict__ mask,
                                                   __hip_bfloat16* __restrict__ attn) {
    __shared__ __align__(16) char smem[49152];
    __hip_bfloat16* Ks = (__hip_bfloat16*)smem;            // [192][64] swizzled
    __hip_bfloat16* Pb = (__hip_bfloat16*)smem;            // [64][192] swizzled (aliases Ks)
    __hip_bfloat16* Vt = (__hip_bfloat16*)(smem + 24576);  // [64][192] swizzled

    const int tid  = threadIdx.x;
    const int lane = tid & 63;
    const int wave = tid >> 6;
    const int fr   = lane & 15;
    const int quad = lane >> 4;

    // XCD-aware swizzle: 1536 blocks = 8 XCDs x 192
    const int bid  = blockIdx.x;
    const int x    = bid & 7;
    const int j    = bid >> 3;                 // 0..191
    const int b    = x >> 1;
    const int q0   = ((x & 1) * 16 + (j & 15)) * 64;
    const int head = j >> 4;                   // 0..11

    const int klo = max(0, q0 - WIN);
    const int khi = min(SEQ, q0 + 64 + WIN);
    const int nk  = khi - klo;     // 128 or 192
    const int nt  = nk >> 4;       // 8 or 12
    const int nkc = nk >> 5;       // 4 or 6

    const size_t rowbase = (size_t)(b * SEQ) * QKV_LD + head * HDIM;

    // ---- stage K [nk][64] XOR-swizzled: up to 1536 uint4 tasks
    for (int task = tid; task < nk * 8; task += 256) {
        int row = task >> 3, g = task & 7;
        uint4 v = *(const uint4*)(qkv + rowbase + (size_t)(klo + row) * QKV_LD + DMODEL + g * 8);
        *(uint4*)(Ks + row * 64 + (g ^ (row & 7)) * 8) = v;
    }
    // ---- stage V transposed [64][nk], XOR-swizzled chunks of 8
    {
        int h = lane;
        const __hip_bfloat16* vb = qkv + rowbase + 2 * DMODEL + h;
        int ng = nk >> 3;
        for (int g = wave; g < ng; g += 4) {
            unsigned int u0, u1, u2, u3;
            {
                unsigned short a0 = *(const unsigned short*)(vb + (size_t)(klo + g * 8 + 0) * QKV_LD);
                unsigned short a1 = *(const unsigned short*)(vb + (size_t)(klo + g * 8 + 1) * QKV_LD);
                unsigned short a2 = *(const unsigned short*)(vb + (size_t)(klo + g * 8 + 2) * QKV_LD);
                unsigned short a3 = *(const unsigned short*)(vb + (size_t)(klo + g * 8 + 3) * QKV_LD);
                unsigned short a4 = *(const unsigned short*)(vb + (size_t)(klo + g * 8 + 4) * QKV_LD);
                unsigned short a5 = *(const unsigned short*)(vb + (size_t)(klo + g * 8 + 5) * QKV_LD);
                unsigned short a6 = *(const unsigned short*)(vb + (size_t)(klo + g * 8 + 6) * QKV_LD);
                unsigned short a7 = *(const unsigned short*)(vb + (size_t)(klo + g * 8 + 7) * QKV_LD);
                u0 = (unsigned int)a0 | ((unsigned int)a1 << 16);
                u1 = (unsigned int)a2 | ((unsigned int)a3 << 16);
                u2 = (unsigned int)a4 | ((unsigned int)a5 << 16);
                u3 = (unsigned int)a6 | ((unsigned int)a7 << 16);
            }
            int cs = g ^ (h & 7);
            *(uint4*)(Vt + h * PLD + cs * 8) = make_uint4(u0, u1, u2, u3);
        }
    }

    // ---- Q fragments direct from global (A-layout: row=fr, k=quad*8+j)
    const int qrow0 = q0 + wave * 16;
    bf16x8 aq0 = *(const bf16x8*)(qkv + rowbase + (size_t)(qrow0 + fr) * QKV_LD + quad * 8);
    bf16x8 aq1 = *(const bf16x8*)(qkv + rowbase + (size_t)(qrow0 + fr) * QKV_LD + 32 + quad * 8);

    const int* mb = mask + b * SEQ;
    int mq[4];
#pragma unroll
    for (int r = 0; r < 4; r++) mq[r] = mb[qrow0 + quad * 4 + r];

    __syncthreads();

    // ---- QK^T via MFMA over key tiles
    f32x4 sc[12];
#pragma unroll
    for (int kt = 0; kt < 12; kt++) sc[kt] = (f32x4){-1e30f, -1e30f, -1e30f, -1e30f};

#pragma unroll
    for (int kt = 0; kt < 12; kt++) {
        if (kt < nt) {
            int krow = kt * 16 + fr;
            int kg = klo + krow;
            int p0 = (quad) ^ (krow & 7);
            int p1 = (4 + quad) ^ (krow & 7);
            bf16x8 bk0 = *(const bf16x8*)(Ks + krow * 64 + p0 * 8);
            bf16x8 bk1 = *(const bf16x8*)(Ks + krow * 64 + p1 * 8);
            f32x4 a = (f32x4){0.f, 0.f, 0.f, 0.f};
            a = __builtin_amdgcn_mfma_f32_16x16x32_bf16(aq0, bk0, a, 0, 0, 0);
            a = __builtin_amdgcn_mfma_f32_16x16x32_bf16(aq1, bk1, a, 0, 0, 0);
            int mk = mb[kg];
            f32x4 s;
#pragma unroll
            for (int r = 0; r < 4; r++) {
                int qg = qrow0 + quad * 4 + r;
                bool ok = (abs(qg - kg) <= WIN) && (mk != 0) && (mq[r] != 0);
                s[r] = ok ? a[r] * 0.125f : -1e30f;
            }
            sc[kt] = s;
        }
    }

    // ---- in-register softmax: reduce across fr lanes (same quad group)
    f32x4 mx = sc[0];
#pragma unroll
    for (int kt = 1; kt < 12; kt++)
#pragma unroll
        for (int r = 0; r < 4; r++) mx[r] = fmaxf(mx[r], sc[kt][r]);
#pragma unroll
    for (int off = 8; off >= 1; off >>= 1)
#pragma unroll
        for (int r = 0; r < 4; r++) mx[r] = fmaxf(mx[r], __shfl_xor(mx[r], off));

    f32x4 sum = (f32x4){0.f, 0.f, 0.f, 0.f};
#pragma unroll
    for (int kt = 0; kt < 12; kt++)
#pragma unroll
        for (int r = 0; r < 4; r++) {
            float e = __expf(sc[kt][r] - mx[r]);
            sc[kt][r] = e;
            sum[r] += e;
        }
#pragma unroll
    for (int off = 8; off >= 1; off >>= 1)
#pragma unroll
        for (int r = 0; r < 4; r++) sum[r] += __shfl_xor(sum[r], off);
    f32x4 rs;
#pragma unroll
    for (int r = 0; r < 4; r++) rs[r] = 1.0f / sum[r];

    // ---- write P (bf16, A-layout-friendly, swizzled) into Ks space
    __syncthreads();   // all waves done reading Ks
#pragma unroll
    for (int kt = 0; kt < 12; kt++) {
        if (kt < nt) {
#pragma unroll
            for (int r = 0; r < 4; r++) {
                int prow = wave * 16 + quad * 4 + r;
                int c = kt * 2 + (fr >> 3);
                int cs = c ^ (prow & 7);
                Pb[prow * PLD + cs * 8 + (fr & 7)] = __float2bfloat16(sc[kt][r] * rs[r]);
            }
        }
    }
    __syncthreads();

    // ---- PV via MFMA: O[16q][64h] per wave
    f32x4 o[4];
#pragma unroll
    for (int ht = 0; ht < 4; ht++) o[ht] = (f32x4){0.f, 0.f, 0.f, 0.f};

#pragma unroll
    for (int kc = 0; kc < 6; kc++) {
        if (kc < nkc) {
            int cs = (kc * 4 + quad) ^ (fr & 7);
            bf16x8 ap = *(const bf16x8*)(Pb + (wave * 16 + fr) * PLD + cs * 8);
#pragma unroll
            for (int ht = 0; ht < 4; ht++) {
                bf16x8 bv = *(const bf16x8*)(Vt + (ht * 16 + fr) * PLD + cs * 8);
                o[ht] = __builtin_amdgcn_mfma_f32_16x16x32_bf16(ap, bv, o[ht], 0, 0, 0);
            }
        }
    }

    // ---- store O (bf16) to attn [B*T, 768]
    __hip_bfloat16* ob = attn + (size_t)(b * SEQ + qrow0) * DMODEL + head * HDIM;
#pragma unroll
    for (int r = 0; r < 4; r++)
#pragma unroll
        for (int ht = 0; ht < 4; ht++)
            ob[(size_t)(quad * 4 + r) * DMODEL + ht * 16 + fr] = __float2bfloat16(o[ht][r]);
}

// ---------------------------------------------------------------------------
extern "C" void kernel_launch(void* const* d_in, const int* in_sizes, int n_in,
                              void* d_out, int out_size, void* d_ws, size_t ws_size,
                              hipStream_t stream) {
    const float* hidden = (const float*)d_in[0];
    const int*   mask   = (const int*)d_in[1];
    const float* Wqkv   = (const float*)d_in[2];
    const float* Wo     = (const float*)d_in[3];
    float* out = (float*)d_out;

    char* w = (char*)d_ws;
    __hip_bfloat16* qkv_bf  = (__hip_bfloat16*)(w);              // 37,748,736
    __hip_bfloat16* hid_bf  = (__hip_bfloat16*)(w + 37748736);   // 12,582,912
    __hip_bfloat16* wqkv_bf = (__hip_bfloat16*)(w + 50331648);   //  3,538,944
    __hip_bfloat16* wo_bf   = (__hip_bfloat16*)(w + 53870592);   //  1,179,648
    __hip_bfloat16* attn_bf = (__hip_bfloat16*)(w + 55050240);   // 12,582,912
    float2*         tab     = (float2*)(w + 67633152);           //    524,288

    // 0) fused setup: casts + rope table (one launch)
    setup_kernel<<<SETUP_TOTAL / 256, 256, 0, stream>>>(hidden, Wqkv, Wo,
                                                        hid_bf, wqkv_bf, wo_bf, tab);

    // 1) QKV projection + fused RoPE (pipelined, 128x128 tiles, 18 n x 64 m)
    gemm_pipe<__hip_bfloat16, true><<<18 * 64, 512, 0, stream>>>(hid_bf, wqkv_bf, qkv_bf,
                                                                 DMODEL, DMODEL, QKV_LD, tab);

    // 2) sliding-window attention (XCD-swizzled 1D grid)
    attn_kernel<<<(SEQ / 64) * NHEADS * BATCH, 256, 0, stream>>>(qkv_bf, mask, attn_bf);

    // 3) output projection (pipelined, 128x128 tiles, 6 n x 64 m)
    gemm_pipe<float, false><<<6 * 64, 512, 0, stream>>>(attn_bf, wo_bf, out,
                                                        DMODEL, DMODEL, DMODEL, nullptr);
}

// Round 3
// 167.685 us; speedup vs baseline: 1.0929x; 1.0158x over previous
//
#include <hip/hip_runtime.h>
#include <hip/hip_bf16.h>
#include <math.h>

// Problem constants (ModernBERT attention)
#define BATCH 4
#define SEQ   2048
#define DMODEL 768
#define NHEADS 12
#define HDIM  64
#define WIN   64          // window each side
#define QKV_LD 2304       // 3*DMODEL

typedef __attribute__((ext_vector_type(8))) short bf16x8;  // 8 bf16 = 4 VGPRs
typedef __attribute__((ext_vector_type(4))) float f32x4;

typedef __attribute__((address_space(1))) const unsigned int guint;
typedef __attribute__((address_space(3))) unsigned int luint;

__device__ inline void gl_lds16(const __hip_bfloat16* g, __hip_bfloat16* l) {
    __builtin_amdgcn_global_load_lds((guint*)g, (luint*)l, 16, 0, 0);
}

__device__ inline void to_out(float* p, float v) { *p = v; }
__device__ inline void to_out(__hip_bfloat16* p, float v) { *p = __float2bfloat16(v); }

// ---------------------------------------------------------------------------
// fused setup: cast hidden/Wqkv/Wo to bf16 + build rope cos/sin table.
// ---------------------------------------------------------------------------
#define N4_HID  (BATCH * SEQ * DMODEL / 4)     // 1,572,864
#define N4_WQKV (QKV_LD * DMODEL / 4)          //   442,368
#define N4_WO   (DMODEL * DMODEL / 4)          //   147,456
#define N_ROPE  (SEQ * 32)                     //    65,536
#define SETUP_TOTAL (N4_HID + N4_WQKV + N4_WO + N_ROPE)

__device__ inline void cast4(const float* in, __hip_bfloat16* out, int i) {
    float4 v = ((const float4*)in)[i];
    union { ushort4 u; __hip_bfloat16 h[4]; } o;
    o.h[0] = __float2bfloat16(v.x); o.h[1] = __float2bfloat16(v.y);
    o.h[2] = __float2bfloat16(v.z); o.h[3] = __float2bfloat16(v.w);
    ((ushort4*)out)[i] = o.u;
}

__global__ __launch_bounds__(256) void setup_kernel(const float* __restrict__ hidden,
                                                    const float* __restrict__ Wqkv,
                                                    const float* __restrict__ Wo,
                                                    __hip_bfloat16* __restrict__ hid_bf,
                                                    __hip_bfloat16* __restrict__ wqkv_bf,
                                                    __hip_bfloat16* __restrict__ wo_bf,
                                                    float2* __restrict__ tab) {
    int id = blockIdx.x * 256 + threadIdx.x;
    if (id < N4_HID) {
        cast4(hidden, hid_bf, id);
    } else if (id < N4_HID + N4_WQKV) {
        cast4(Wqkv, wqkv_bf, id - N4_HID);
    } else if (id < N4_HID + N4_WQKV + N4_WO) {
        cast4(Wo, wo_bf, id - N4_HID - N4_WQKV);
    } else if (id < SETUP_TOTAL) {
        int idx = id - (N4_HID + N4_WQKV + N4_WO);
        int t = idx >> 5, j = idx & 31;
        const float L2T_OVER_32 = 13.287712379549449f / 32.0f;  // log2(10000)/32
        float inv = exp2f(-(float)j * L2T_OVER_32);
        float s, c;
        sincosf((float)t * inv, &s, &c);
        tab[idx] = make_float2(c, s);
    }
}

// ---------------------------------------------------------------------------
// Pipelined bf16 MFMA NT GEMM: C[m,n] = sum_k A[m*lda+k]*B[n*ldb+k]
// BM=128, BN=128, BK=64, K=768 fixed (12 K-tiles). 256 threads = 4 waves,
// 2x2 wave decomposition -> per-wave 64x64 output: 16 ds_read_b128 per
// 32 MFMA (2.0 MFMA/read; R2's 8-wave 32x64 tile was 1.33 -> LDS-traffic
// bound). 2-slot LDS ring (64 KB) -> 2 blocks/CU so a co-resident block
// hides barrier/vmcnt stalls (R2's 128 KB ring capped at 1 block/CU,
// OccupancyPercent 16.8%).
// Per K-tile: s_waitcnt vmcnt(8) (retire own tile-t loads, tile-t+1's 8
// stay in flight) -> raw s_barrier -> compute(t) -> s_barrier ->
// stage(t+2) into the slot tile t-? just vacated. All waves wait their own
// loads before the pre-compute barrier, so after it ALL of tile t's LDS
// writes are visible. Tail: vmcnt(0) at t=11; no post-barrier after t=9.
// Staging/fragment XOR-8 swizzle identical to the verified R0 kernel.
// setprio(1) around MFMA clusters. XCD-aware 1D grid as before.
// ---------------------------------------------------------------------------
template <typename OutT, bool ROPE>
__global__ __launch_bounds__(256) void gemm_db(const __hip_bfloat16* __restrict__ A,
                                               const __hip_bfloat16* __restrict__ B,
                                               OutT* __restrict__ C,
                                               int lda, int ldb, int ldc,
                                               const float2* __restrict__ rope_tab) {
    __shared__ __align__(16) char smem[65536];
    __hip_bfloat16* As = (__hip_bfloat16*)smem;            // [2][128*64]
    __hip_bfloat16* Bs = (__hip_bfloat16*)(smem + 32768);  // [2][128*64]

    const int tid  = threadIdx.x;
    const int lane = tid & 63;
    const int wave = tid >> 6;   // 0..3
    const int wm   = wave >> 1;  // 0..1  (64-row band)
    const int wn   = wave & 1;   // 0..1  (64-col band)
    const int fr   = lane & 15;
    const int quad = lane >> 4;

    // XCD-aware swizzle (gridM = 64 m-tiles, 8 per XCD)
    const int bid = blockIdx.x;
    const int x   = bid & 7;
    const int j   = bid >> 3;
    const int m0  = (x * 8 + (j & 7)) * 128;
    const int n0  = (j >> 3) * 128;

    f32x4 acc[4][4];
#pragma unroll
    for (int i = 0; i < 4; i++)
#pragma unroll
        for (int jj = 0; jj < 4; jj++) acc[i][jj] = (f32x4){0.f, 0.f, 0.f, 0.f};

    // stage one 128x64 A-tile + 128x64 B-tile into ring slot t&1.
    // 1024 16B-chunks each over 256 threads -> 4 A + 4 B loads per thread.
    auto stage = [&](int t) {
        const int s  = t & 1;
        const int k0 = t * 64;
#pragma unroll
        for (int c = 0; c < 4; ++c) {
            int tc  = (wave * 4 + c) * 64 + lane;   // 0..1023
            int row = tc >> 3, ch = tc & 7;
            int gcol = (ch ^ (row & 7)) * 8;
            gl_lds16(A + (size_t)(m0 + row) * lda + k0 + gcol, As + s * 8192 + tc * 8);
        }
#pragma unroll
        for (int c = 0; c < 4; ++c) {
            int tc  = (wave * 4 + c) * 64 + lane;
            int row = tc >> 3, ch = tc & 7;
            int gcol = (ch ^ (row & 7)) * 8;
            gl_lds16(B + (size_t)(n0 + row) * ldb + k0 + gcol, Bs + s * 8192 + tc * 8);
        }
    };

    // prologue: 2 tiles in flight (16 loads/wave)
    stage(0); stage(1);

#pragma unroll
    for (int t = 0; t < 12; ++t) {
        // retire tile t's 8 loads (wave-local); tile t+1's 8 stay in flight.
        if (t < 11) asm volatile("s_waitcnt vmcnt(8)" ::: "memory");
        else        asm volatile("s_waitcnt vmcnt(0)" ::: "memory");
        __builtin_amdgcn_s_barrier();          // raw: no implicit drain
        __builtin_amdgcn_sched_barrier(0);     // pin: no reads hoisted above

        const __hip_bfloat16* as = As + (t & 1) * 8192;
        const __hip_bfloat16* bs = Bs + (t & 1) * 8192;
#pragma unroll
        for (int ks = 0; ks < 2; ++ks) {
            bf16x8 af[4], bfv[4];
#pragma unroll
            for (int mi = 0; mi < 4; ++mi) {
                int row = wm * 64 + mi * 16 + fr;
                int pos = (ks * 4 + quad) ^ (row & 7);
                af[mi] = *(const bf16x8*)(as + row * 64 + pos * 8);
            }
#pragma unroll
            for (int ni = 0; ni < 4; ++ni) {
                int row = wn * 64 + ni * 16 + fr;
                int pos = (ks * 4 + quad) ^ (row & 7);
                bfv[ni] = *(const bf16x8*)(bs + row * 64 + pos * 8);
            }
            __builtin_amdgcn_s_setprio(1);
#pragma unroll
            for (int mi = 0; mi < 4; ++mi)
#pragma unroll
                for (int ni = 0; ni < 4; ++ni)
                    acc[mi][ni] = __builtin_amdgcn_mfma_f32_16x16x32_bf16(af[mi], bfv[ni], acc[mi][ni], 0, 0, 0);
            __builtin_amdgcn_s_setprio(0);
        }

        if (t < 10) {
            __builtin_amdgcn_s_barrier();      // all waves done reading slot t&1
            __builtin_amdgcn_sched_barrier(0);
            stage(t + 2);                      // refill the vacated slot
        }
    }

    // fused RoPE: 64-col group b0 covers exactly one head; pairs (ni, ni+2)
    const int b0 = n0 + wn * 64;
    if (ROPE && b0 < 2 * DMODEL) {
#pragma unroll
        for (int mi = 0; mi < 4; mi++) {
#pragma unroll
            for (int r = 0; r < 4; r++) {
                int t = (m0 + wm * 64 + mi * 16 + quad * 4 + r) & (SEQ - 1);
#pragma unroll
                for (int ni = 0; ni < 2; ni++) {
                    float2 cs = rope_tab[t * 32 + ni * 16 + fr];
                    float x0 = acc[mi][ni][r], x1 = acc[mi][ni + 2][r];
                    acc[mi][ni][r]     = x0 * cs.x - x1 * cs.y;
                    acc[mi][ni + 2][r] = x0 * cs.y + x1 * cs.x;
                }
            }
        }
    }

    // direct scalar-store epilogue (no barriers)
#pragma unroll
    for (int mi = 0; mi < 4; mi++)
#pragma unroll
        for (int ni = 0; ni < 4; ni++) {
            f32x4 v = acc[mi][ni];
            int gc = b0 + ni * 16 + fr;
            size_t rbase = (size_t)(m0 + wm * 64 + mi * 16 + quad * 4);
#pragma unroll
            for (int r = 0; r < 4; r++)
                to_out(&C[(rbase + r) * ldc + gc], v[r]);
        }
}

// ---------------------------------------------------------------------------
// Sliding-window attention, one block per (b, head, 64-query tile).
// QK^T and PV via MFMA; in-register softmax via quad-group shuffles.
// Q fragments loaded directly from global. K staged stride 64 + XOR swizzle.
// LDS 48 KB -> 3 blocks/CU.
// ---------------------------------------------------------------------------
#define PLD  192

__global__ __launch_bounds__(256) void attn_kernel(const __hip_bfloat16* __restrict__ qkv,
                                                   const int* __restrict__ mask,
                                                   __hip_bfloat16* __restrict__ attn) {
    __shared__ __align__(16) char smem[49152];
    __hip_bfloat16* Ks = (__hip_bfloat16*)smem;            // [192][64] swizzled
    __hip_bfloat16* Pb = (__hip_bfloat16*)smem;            // [64][192] swizzled (aliases Ks)
    __hip_bfloat16* Vt = (__hip_bfloat16*)(smem + 24576);  // [64][192] swizzled

    const int tid  = threadIdx.x;
    const int lane = tid & 63;
    const int wave = tid >> 6;
    const int fr   = lane & 15;
    const int quad = lane >> 4;

    // XCD-aware swizzle: 1536 blocks = 8 XCDs x 192
    const int bid  = blockIdx.x;
    const int x    = bid & 7;
    const int j    = bid >> 3;                 // 0..191
    const int b    = x >> 1;
    const int q0   = ((x & 1) * 16 + (j & 15)) * 64;
    const int head = j >> 4;                   // 0..11

    const int klo = max(0, q0 - WIN);
    const int khi = min(SEQ, q0 + 64 + WIN);
    const int nk  = khi - klo;     // 128 or 192
    const int nt  = nk >> 4;       // 8 or 12
    const int nkc = nk >> 5;       // 4 or 6

    const size_t rowbase = (size_t)(b * SEQ) * QKV_LD + head * HDIM;

    // ---- stage K [nk][64] XOR-swizzled: up to 1536 uint4 tasks
    for (int task = tid; task < nk * 8; task += 256) {
        int row = task >> 3, g = task & 7;
        uint4 v = *(const uint4*)(qkv + rowbase + (size_t)(klo + row) * QKV_LD + DMODEL + g * 8);
        *(uint4*)(Ks + row * 64 + (g ^ (row & 7)) * 8) = v;
    }
    // ---- stage V transposed [64][nk], XOR-swizzled chunks of 8
    {
        int h = lane;
        const __hip_bfloat16* vb = qkv + rowbase + 2 * DMODEL + h;
        int ng = nk >> 3;
        for (int g = wave; g < ng; g += 4) {
            unsigned int u0, u1, u2, u3;
            {
                unsigned short a0 = *(const unsigned short*)(vb + (size_t)(klo + g * 8 + 0) * QKV_LD);
                unsigned short a1 = *(const unsigned short*)(vb + (size_t)(klo + g * 8 + 1) * QKV_LD);
                unsigned short a2 = *(const unsigned short*)(vb + (size_t)(klo + g * 8 + 2) * QKV_LD);
                unsigned short a3 = *(const unsigned short*)(vb + (size_t)(klo + g * 8 + 3) * QKV_LD);
                unsigned short a4 = *(const unsigned short*)(vb + (size_t)(klo + g * 8 + 4) * QKV_LD);
                unsigned short a5 = *(const unsigned short*)(vb + (size_t)(klo + g * 8 + 5) * QKV_LD);
                unsigned short a6 = *(const unsigned short*)(vb + (size_t)(klo + g * 8 + 6) * QKV_LD);
                unsigned short a7 = *(const unsigned short*)(vb + (size_t)(klo + g * 8 + 7) * QKV_LD);
                u0 = (unsigned int)a0 | ((unsigned int)a1 << 16);
                u1 = (unsigned int)a2 | ((unsigned int)a3 << 16);
                u2 = (unsigned int)a4 | ((unsigned int)a5 << 16);
                u3 = (unsigned int)a6 | ((unsigned int)a7 << 16);
            }
            int cs = g ^ (h & 7);
            *(uint4*)(Vt + h * PLD + cs * 8) = make_uint4(u0, u1, u2, u3);
        }
    }

    // ---- Q fragments direct from global (A-layout: row=fr, k=quad*8+j)
    const int qrow0 = q0 + wave * 16;
    bf16x8 aq0 = *(const bf16x8*)(qkv + rowbase + (size_t)(qrow0 + fr) * QKV_LD + quad * 8);
    bf16x8 aq1 = *(const bf16x8*)(qkv + rowbase + (size_t)(qrow0 + fr) * QKV_LD + 32 + quad * 8);

    const int* mb = mask + b * SEQ;
    int mq[4];
#pragma unroll
    for (int r = 0; r < 4; r++) mq[r] = mb[qrow0 + quad * 4 + r];

    __syncthreads();

    // ---- QK^T via MFMA over key tiles
    f32x4 sc[12];
#pragma unroll
    for (int kt = 0; kt < 12; kt++) sc[kt] = (f32x4){-1e30f, -1e30f, -1e30f, -1e30f};

#pragma unroll
    for (int kt = 0; kt < 12; kt++) {
        if (kt < nt) {
            int krow = kt * 16 + fr;
            int kg = klo + krow;
            int p0 = (quad) ^ (krow & 7);
            int p1 = (4 + quad) ^ (krow & 7);
            bf16x8 bk0 = *(const bf16x8*)(Ks + krow * 64 + p0 * 8);
            bf16x8 bk1 = *(const bf16x8*)(Ks + krow * 64 + p1 * 8);
            f32x4 a = (f32x4){0.f, 0.f, 0.f, 0.f};
            a = __builtin_amdgcn_mfma_f32_16x16x32_bf16(aq0, bk0, a, 0, 0, 0);
            a = __builtin_amdgcn_mfma_f32_16x16x32_bf16(aq1, bk1, a, 0, 0, 0);
            int mk = mb[kg];
            f32x4 s;
#pragma unroll
            for (int r = 0; r < 4; r++) {
                int qg = qrow0 + quad * 4 + r;
                bool ok = (abs(qg - kg) <= WIN) && (mk != 0) && (mq[r] != 0);
                s[r] = ok ? a[r] * 0.125f : -1e30f;
            }
            sc[kt] = s;
        }
    }

    // ---- in-register softmax: reduce across fr lanes (same quad group)
    f32x4 mx = sc[0];
#pragma unroll
    for (int kt = 1; kt < 12; kt++)
#pragma unroll
        for (int r = 0; r < 4; r++) mx[r] = fmaxf(mx[r], sc[kt][r]);
#pragma unroll
    for (int off = 8; off >= 1; off >>= 1)
#pragma unroll
        for (int r = 0; r < 4; r++) mx[r] = fmaxf(mx[r], __shfl_xor(mx[r], off));

    f32x4 sum = (f32x4){0.f, 0.f, 0.f, 0.f};
#pragma unroll
    for (int kt = 0; kt < 12; kt++)
#pragma unroll
        for (int r = 0; r < 4; r++) {
            float e = __expf(sc[kt][r] - mx[r]);
            sc[kt][r] = e;
            sum[r] += e;
        }
#pragma unroll
    for (int off = 8; off >= 1; off >>= 1)
#pragma unroll
        for (int r = 0; r < 4; r++) sum[r] += __shfl_xor(sum[r], off);
    f32x4 rs;
#pragma unroll
    for (int r = 0; r < 4; r++) rs[r] = 1.0f / sum[r];

    // ---- write P (bf16, A-layout-friendly, swizzled) into Ks space
    __syncthreads();   // all waves done reading Ks
#pragma unroll
    for (int kt = 0; kt < 12; kt++) {
        if (kt < nt) {
#pragma unroll
            for (int r = 0; r < 4; r++) {
                int prow = wave * 16 + quad * 4 + r;
                int c = kt * 2 + (fr >> 3);
                int cs = c ^ (prow & 7);
                Pb[prow * PLD + cs * 8 + (fr & 7)] = __float2bfloat16(sc[kt][r] * rs[r]);
            }
        }
    }
    __syncthreads();

    // ---- PV via MFMA: O[16q][64h] per wave
    f32x4 o[4];
#pragma unroll
    for (int ht = 0; ht < 4; ht++) o[ht] = (f32x4){0.f, 0.f, 0.f, 0.f};

#pragma unroll
    for (int kc = 0; kc < 6; kc++) {
        if (kc < nkc) {
            int cs = (kc * 4 + quad) ^ (fr & 7);
            bf16x8 ap = *(const bf16x8*)(Pb + (wave * 16 + fr) * PLD + cs * 8);
#pragma unroll
            for (int ht = 0; ht < 4; ht++) {
                bf16x8 bv = *(const bf16x8*)(Vt + (ht * 16 + fr) * PLD + cs * 8);
                o[ht] = __builtin_amdgcn_mfma_f32_16x16x32_bf16(ap, bv, o[ht], 0, 0, 0);
            }
        }
    }

    // ---- store O (bf16) to attn [B*T, 768]
    __hip_bfloat16* ob = attn + (size_t)(b * SEQ + qrow0) * DMODEL + head * HDIM;
#pragma unroll
    for (int r = 0; r < 4; r++)
#pragma unroll
        for (int ht = 0; ht < 4; ht++)
            ob[(size_t)(quad * 4 + r) * DMODEL + ht * 16 + fr] = __float2bfloat16(o[ht][r]);
}

// ---------------------------------------------------------------------------
extern "C" void kernel_launch(void* const* d_in, const int* in_sizes, int n_in,
                              void* d_out, int out_size, void* d_ws, size_t ws_size,
                              hipStream_t stream) {
    const float* hidden = (const float*)d_in[0];
    const int*   mask   = (const int*)d_in[1];
    const float* Wqkv   = (const float*)d_in[2];
    const float* Wo     = (const float*)d_in[3];
    float* out = (float*)d_out;

    char* w = (char*)d_ws;
    __hip_bfloat16* qkv_bf  = (__hip_bfloat16*)(w);              // 37,748,736
    __hip_bfloat16* hid_bf  = (__hip_bfloat16*)(w + 37748736);   // 12,582,912
    __hip_bfloat16* wqkv_bf = (__hip_bfloat16*)(w + 50331648);   //  3,538,944
    __hip_bfloat16* wo_bf   = (__hip_bfloat16*)(w + 53870592);   //  1,179,648
    __hip_bfloat16* attn_bf = (__hip_bfloat16*)(w + 55050240);   // 12,582,912
    float2*         tab     = (float2*)(w + 67633152);           //    524,288

    // 0) fused setup: casts + rope table (one launch)
    setup_kernel<<<SETUP_TOTAL / 256, 256, 0, stream>>>(hidden, Wqkv, Wo,
                                                        hid_bf, wqkv_bf, wo_bf, tab);

    // 1) QKV projection + fused RoPE (pipelined 2-slot ring, 128x128 tiles)
    gemm_db<__hip_bfloat16, true><<<18 * 64, 256, 0, stream>>>(hid_bf, wqkv_bf, qkv_bf,
                                                               DMODEL, DMODEL, QKV_LD, tab);

    // 2) sliding-window attention (XCD-swizzled 1D grid)
    attn_kernel<<<(SEQ / 64) * NHEADS * BATCH, 256, 0, stream>>>(qkv_bf, mask, attn_bf);

    // 3) output projection (pipelined 2-slot ring, 128x128 tiles)
    gemm_db<float, false><<<6 * 64, 256, 0, stream>>>(attn_bf, wo_bf, out,
                                                      DMODEL, DMODEL, DMODEL, nullptr);
}